// Round 12
// baseline (6175.042 us; speedup 1.0000x reference)
//
#include <hip/hip_runtime.h>
#include <math.h>

// Problem constants
#define NN 4096
#define TT 48
#define HH 64
#define GG 256   // 4*H
#define PP 12
#define CAP 192  // ELL slots per row, 3 x 64 -> whole-wave chunk loads, no guard
#define NH (NN * HH)

// readlane broadcast: uniform lane index -> SGPR broadcast, off the LDS pipe
__device__ __forceinline__ float bcast_f(float v, int lane) {
  return __int_as_float(__builtin_amdgcn_readlane(__float_as_int(v), lane));
}
__device__ __forceinline__ int bcast_i(int v, int lane) {
  return __builtin_amdgcn_readlane(v, lane);
}

// ---------------------------------------------------------------------------
// h-state: paired buffers P[2], each [N][64][2]: {h0, h1} interleaved.
// Launch k (k=0..48) computes cell0(t=k) [k<48] and cell1(s=k-1) [k>0]:
//   READS only P[(k&1)^1], WRITES only P[k&1] (disjoint float2 slots).
// GATE-QUAD mapping: lane j owns cols {j, j+64, j+128, j+192}.
// K-SPLIT (R11->R12): within a block, wave w owns k-range [16w, 16w+16) for
// ALL 8 rows -> each weight float4 loaded once per BLOCK (was once per wave;
// weight streaming was the R11 stall: 3MB/CU/launch of private L2 traffic).
// Partial combs reduced in LDS; wave 0 applies gates.
//   Wg0[(k*2+m)*64+j] = float4 gate-quad, m in {gcWh0, liWh0}
//   Wg1[(k*4+m)*64+j] = float4 gate-quad, m in {gcWi1, liWi1, gcWh1, liWh1}
// ---------------------------------------------------------------------------
__launch_bounds__(256)
__global__ void k_prep(const float* gcbi0, const float* gcbh0,
                       const float* libi0, const float* libh0,
                       const float* gcbi1, const float* gcbh1,
                       const float* libi1, const float* libh1,
                       const float* gcWh0, const float* liWh0,
                       const float* gcWi1, const float* liWi1,
                       const float* gcWh1, const float* liWh1,
                       const float* gcWi0, const float* liWi0,
                       float* state, float4* Wg0, float4* Wg1,
                       float4* biasg0, float4* biasg1, float4* xq0) {
  int idx = blockIdx.x * 256 + threadIdx.x;
  int stride = gridDim.x * 256;
  for (int i = idx; i < 6 * NH; i += stride) state[i] = 0.0f;  // P0,P1,c0,c1
  for (int i = idx; i < 64 * 2 * 64; i += stride) {
    int j = i & 63, m = (i >> 6) & 1, k = i >> 7;
    const float* W = m ? liWh0 : gcWh0;
    Wg0[i] = make_float4(W[k * GG + j], W[k * GG + j + 64],
                         W[k * GG + j + 128], W[k * GG + j + 192]);
  }
  for (int i = idx; i < 64 * 4 * 64; i += stride) {
    int j = i & 63, m = (i >> 6) & 3, k = i >> 8;
    const float* W = (m == 0) ? gcWi1 : (m == 1) ? liWi1 : (m == 2) ? gcWh1 : liWh1;
    Wg1[i] = make_float4(W[k * GG + j], W[k * GG + j + 64],
                         W[k * GG + j + 128], W[k * GG + j + 192]);
  }
  if (idx < 64) {
    int j = idx;
    biasg0[j] = make_float4(
        gcbi0[j] + gcbh0[j] + libi0[j] + libh0[j],
        gcbi0[j + 64] + gcbh0[j + 64] + libi0[j + 64] + libh0[j + 64],
        gcbi0[j + 128] + gcbh0[j + 128] + libi0[j + 128] + libh0[j + 128],
        gcbi0[j + 192] + gcbh0[j + 192] + libi0[j + 192] + libh0[j + 192]);
    biasg1[j] = make_float4(
        gcbi1[j] + gcbh1[j] + libi1[j] + libh1[j],
        gcbi1[j + 64] + gcbh1[j + 64] + libi1[j + 64] + libh1[j + 64],
        gcbi1[j + 128] + gcbh1[j + 128] + libi1[j + 128] + libh1[j + 128],
        gcbi1[j + 192] + gcbh1[j + 192] + libi1[j + 192] + libh1[j + 192]);
  } else if (idx < 320) {
    int i = idx - 64;           // i = m*64 + j
    int j = i & 63, m = i >> 6; // m: 0,1 -> gcWi0 row 0/1; 2,3 -> liWi0 row 0/1
    const float* W = (m < 2) ? gcWi0 : liWi0;
    int kk = m & 1;
    xq0[i] = make_float4(W[kk * GG + j], W[kk * GG + j + 64],
                         W[kk * GG + j + 128], W[kk * GG + j + 192]);
  }
}

// ---------------------------------------------------------------------------
// Single adj pass: raw ELL (incl. +I diag) + dinv. Zero-fills ALL CAP slots
// (re-poison semantics: padding must be (col=0, val=0)). cnt padded to x8.
// ---------------------------------------------------------------------------
__launch_bounds__(256)
__global__ void k_build(const float* adj, float* dinv,
                        int* ell_col, float* ell_val, int* ell_cnt) {
  int r = blockIdx.x;
  __shared__ int cnt;
  __shared__ float red[256];
  if (threadIdx.x == 0) cnt = 0;
  __syncthreads();
  const float* row = adj + (size_t)r * NN;
  float s = 0.0f;
  for (int c = threadIdx.x; c < NN; c += 256) {
    float a = row[c];
    if (c == r) a += 1.0f;   // A = adj + I
    s += a;
    if (a != 0.0f) {
      int pos = atomicAdd(&cnt, 1);
      if (pos < CAP) {
        ell_col[(size_t)r * CAP + pos] = c;
        ell_val[(size_t)r * CAP + pos] = a;
      }
    }
  }
  red[threadIdx.x] = s;
  __syncthreads();
  for (int st = 128; st > 0; st >>= 1) {
    if (threadIdx.x < st) red[threadIdx.x] += red[threadIdx.x + st];
    __syncthreads();
  }
  int n = cnt < CAP ? cnt : CAP;
  for (int j = n + (int)threadIdx.x; j < CAP; j += 256) {
    ell_col[(size_t)r * CAP + j] = 0;
    ell_val[(size_t)r * CAP + j] = 0.0f;
  }
  if (threadIdx.x == 0) {
    int npad = (n + 7) & ~7;
    if (npad > CAP) npad = CAP;
    ell_cnt[r] = npad;
    dinv[r] = 1.0f / sqrtf(red[0]);  // rowsum + 1 >= 1
  }
}

__launch_bounds__(256)
__global__ void k_scale(const float* dinv, const int* ell_col, float* ell_val) {
  int idx = blockIdx.x * 256 + threadIdx.x;  // over NN*CAP
  int r = idx / CAP;
  if (r >= NN) return;
  float v = ell_val[idx];
  if (v != 0.0f) ell_val[idx] = v * dinv[r] * dinv[ell_col[idx]];
}

// ---------------------------------------------------------------------------
// Precompute gax[t][r][c] = (A @ x_t)[r][c]. Block = (t, 512-row segment).
// ---------------------------------------------------------------------------
__launch_bounds__(256)
__global__ void k_gax(const float* x, const int* ell_col, const float* ell_val,
                      const int* ell_cnt, float* gax) {
  int t = blockIdx.x >> 3;
  int seg = blockIdx.x & 7;
  __shared__ float xs[NN * 2];
  const float* xt = x + (size_t)t * NN * 2;
  for (int i = threadIdx.x; i < NN * 2; i += 256) xs[i] = xt[i];
  __syncthreads();
  int base = seg * 512 * 2;
  for (int oo = threadIdx.x; oo < 512 * 2; oo += 256) {
    int o = base + oo;
    int r = o >> 1, cmp = o & 1;
    int cnt = ell_cnt[r];
    const int* cp = ell_col + (size_t)r * CAP;
    const float* vp = ell_val + (size_t)r * CAP;
    float acc = 0.0f;
    for (int j = 0; j < cnt; j += 4) {
      acc += vp[j]     * xs[cp[j]     * 2 + cmp];
      acc += vp[j + 1] * xs[cp[j + 1] * 2 + cmp];
      acc += vp[j + 2] * xs[cp[j + 2] * 2 + cmp];
      acc += vp[j + 3] * xs[cp[j + 3] * 2 + cmp];
    }
    gax[(size_t)t * NN * 2 + o] = acc;
  }
}

#define ASTR 65   // act LDS stride (floats) — breaks bank alignment

// ---------------------------------------------------------------------------
// Cell 0 body, k-split. LDS: actS0 [8r][2m][ASTR], redS 3x512 float4.
// ---------------------------------------------------------------------------
__device__ __forceinline__ void cell0_body(
    int blk, float* actS, float4* redS,
    const int* __restrict__ ell_col, const float* __restrict__ ell_val,
    const int* __restrict__ ell_cnt,
    const float2* __restrict__ Pr, float* __restrict__ Pw,
    float* __restrict__ c0,
    const float* __restrict__ xt, const float* __restrict__ gaxt,
    const float4* __restrict__ Wg0, const float4* __restrict__ biasg0,
    const float4* __restrict__ xq0) {
  const int tid = threadIdx.x;
  const int wave = tid >> 6, lane = tid & 63;
  const int r0 = blk * 8;

  // phase 1: wave w gathers rows 2w, 2w+1
#pragma unroll
  for (int rr = 0; rr < 2; rr++) {
    int rloc = 2 * wave + rr;
    int r = r0 + rloc;
    int cnt = ell_cnt[r];
    float acc = 0.0f;
#pragma unroll
    for (int chk = 0; chk < 3; chk++) {
      int base = chk * 64;
      if (base < cnt) {
        int lim = cnt - base; if (lim > 64) lim = 64;  // multiple of 8
        int mc = ell_col[(size_t)r * CAP + base + lane];
        float mv = ell_val[(size_t)r * CAP + base + lane];
        for (int m = 0; m < lim; m += 8) {
          float2 ld[8]; float vv[8];
#pragma unroll
          for (int i = 0; i < 8; i++) {
            int cc = bcast_i(mc, m + i);
            vv[i] = bcast_f(mv, m + i);
            ld[i] = Pr[(size_t)cc * 64 + lane];
          }
#pragma unroll
          for (int i = 0; i < 8; i++) acc += vv[i] * ld[i].x;
        }
      }
    }
    actS[(rloc * 2 + 0) * ASTR + lane] = acc;
    actS[(rloc * 2 + 1) * ASTR + lane] = Pr[(size_t)r * 64 + lane].x;
  }
  __syncthreads();

  // phase 2: wave w covers k in [16w, 16w+16) for all 8 rows
  const int kk0 = wave * 16;
  const int lm = lane & 1, lk = (lane >> 1) & 15;  // lane slot (m, kk); dup for lane>=32
  float areg[8];
#pragma unroll
  for (int r = 0; r < 8; r++)
    areg[r] = actS[(r * 2 + lm) * ASTR + kk0 + lk];

  float4 acc[8];
  if (wave == 0) {
    float4 b = biasg0[lane];
    float4 qg0 = xq0[lane], qg1 = xq0[64 + lane];
    float4 ql0 = xq0[128 + lane], ql1 = xq0[192 + lane];
#pragma unroll
    for (int r = 0; r < 8; r++) {
      float xx0 = xt[(size_t)(r0 + r) * 2];
      float xx1 = xt[(size_t)(r0 + r) * 2 + 1];
      float gg0 = gaxt[(size_t)(r0 + r) * 2];
      float gg1 = gaxt[(size_t)(r0 + r) * 2 + 1];
      acc[r].x = b.x + gg0 * qg0.x + gg1 * qg1.x + xx0 * ql0.x + xx1 * ql1.x;
      acc[r].y = b.y + gg0 * qg0.y + gg1 * qg1.y + xx0 * ql0.y + xx1 * ql1.y;
      acc[r].z = b.z + gg0 * qg0.z + gg1 * qg1.z + xx0 * ql0.z + xx1 * ql1.z;
      acc[r].w = b.w + gg0 * qg0.w + gg1 * qg1.w + xx0 * ql0.w + xx1 * ql1.w;
    }
  } else {
#pragma unroll
    for (int r = 0; r < 8; r++) acc[r] = make_float4(0.f, 0.f, 0.f, 0.f);
  }

  const float4* bw = Wg0 + lane;
#pragma unroll
  for (int kk = 0; kk < 16; kk++) {
    int k = kk0 + kk;
    float4 w0 = bw[(k * 2 + 0) * 64];
    float4 w1 = bw[(k * 2 + 1) * 64];
#pragma unroll
    for (int r = 0; r < 8; r++) {
      float a0 = bcast_f(areg[r], kk * 2 + 0);
      float a1 = bcast_f(areg[r], kk * 2 + 1);
      acc[r].x += a0 * w0.x + a1 * w1.x;
      acc[r].y += a0 * w0.y + a1 * w1.y;
      acc[r].z += a0 * w0.z + a1 * w1.z;
      acc[r].w += a0 * w0.w + a1 * w1.w;
    }
  }

  // phase 3: waves 1-3 deposit partials; wave 0 reduces + gates
  if (wave > 0) {
#pragma unroll
    for (int r = 0; r < 8; r++)
      redS[(wave - 1) * 512 + r * 64 + lane] = acc[r];
  }
  __syncthreads();
  if (wave == 0) {
#pragma unroll
    for (int r = 0; r < 8; r++) {
      float4 t = acc[r];
#pragma unroll
      for (int w = 0; w < 3; w++) {
        float4 p = redS[w * 512 + r * 64 + lane];
        t.x += p.x; t.y += p.y; t.z += p.z; t.w += p.w;
      }
      size_t gi = (size_t)(r0 + r) * HH + lane;
      float cprev = c0[gi];
      float si = 1.0f / (1.0f + __expf(-t.x));
      float sf = 1.0f / (1.0f + __expf(-t.y));
      float so = 1.0f / (1.0f + __expf(-t.z));
      float cn = sf * cprev + si * tanhf(t.w);
      float hn = so * tanhf(cn);
      c0[gi] = cn;
      Pw[gi * 2 + 0] = hn;
    }
  }
}

// ---------------------------------------------------------------------------
// Cell 1 body, k-split. LDS: actS [8r][4m][ASTR], redS 3x512 float4.
// ---------------------------------------------------------------------------
__device__ __forceinline__ void cell1_body(
    int blk, float* actS, float4* redS,
    const int* __restrict__ ell_col, const float* __restrict__ ell_val,
    const int* __restrict__ ell_cnt,
    const float2* __restrict__ Pr, float* __restrict__ Pw,
    float* __restrict__ c1,
    const float4* __restrict__ Wg1, const float4* __restrict__ biasg1) {
  const int tid = threadIdx.x;
  const int wave = tid >> 6, lane = tid & 63;
  const int r0 = blk * 8;

  // phase 1: wave w gathers rows 2w, 2w+1 (dual: {h0n, h1old})
#pragma unroll
  for (int rr = 0; rr < 2; rr++) {
    int rloc = 2 * wave + rr;
    int r = r0 + rloc;
    int cnt = ell_cnt[r];
    float a0 = 0.0f, a1 = 0.0f;
#pragma unroll
    for (int chk = 0; chk < 3; chk++) {
      int base = chk * 64;
      if (base < cnt) {
        int lim = cnt - base; if (lim > 64) lim = 64;  // multiple of 8
        int mc = ell_col[(size_t)r * CAP + base + lane];
        float mv = ell_val[(size_t)r * CAP + base + lane];
        for (int m = 0; m < lim; m += 8) {
          float2 ld[8]; float vv[8];
#pragma unroll
          for (int i = 0; i < 8; i++) {
            int cc = bcast_i(mc, m + i);
            vv[i] = bcast_f(mv, m + i);
            ld[i] = Pr[(size_t)cc * 64 + lane];
          }
#pragma unroll
          for (int i = 0; i < 8; i++) {
            a0 += vv[i] * ld[i].x;
            a1 += vv[i] * ld[i].y;
          }
        }
      }
    }
    float2 hh = Pr[(size_t)r * 64 + lane];
    actS[(rloc * 4 + 0) * ASTR + lane] = a0;
    actS[(rloc * 4 + 1) * ASTR + lane] = hh.x;
    actS[(rloc * 4 + 2) * ASTR + lane] = a1;
    actS[(rloc * 4 + 3) * ASTR + lane] = hh.y;
  }
  __syncthreads();

  // phase 2: wave w covers k in [16w, 16w+16) for all 8 rows
  const int kk0 = wave * 16;
  const int lm = lane & 3, lk = lane >> 2;  // lane slot: (m, kk), 64 lanes exact
  float areg[8];
#pragma unroll
  for (int r = 0; r < 8; r++)
    areg[r] = actS[(r * 4 + lm) * ASTR + kk0 + lk];

  float4 acc[8];
  if (wave == 0) {
    float4 b = biasg1[lane];
#pragma unroll
    for (int r = 0; r < 8; r++) acc[r] = b;
  } else {
#pragma unroll
    for (int r = 0; r < 8; r++) acc[r] = make_float4(0.f, 0.f, 0.f, 0.f);
  }

  const float4* bw = Wg1 + lane;
#pragma unroll
  for (int kk = 0; kk < 16; kk++) {
    int k = kk0 + kk;
    float4 w0 = bw[(k * 4 + 0) * 64];
    float4 w1 = bw[(k * 4 + 1) * 64];
    float4 w2 = bw[(k * 4 + 2) * 64];
    float4 w3 = bw[(k * 4 + 3) * 64];
#pragma unroll
    for (int r = 0; r < 8; r++) {
      float a0 = bcast_f(areg[r], kk * 4 + 0);
      float a1 = bcast_f(areg[r], kk * 4 + 1);
      float a2 = bcast_f(areg[r], kk * 4 + 2);
      float a3 = bcast_f(areg[r], kk * 4 + 3);
      acc[r].x += a0 * w0.x + a1 * w1.x + a2 * w2.x + a3 * w3.x;
      acc[r].y += a0 * w0.y + a1 * w1.y + a2 * w2.y + a3 * w3.y;
      acc[r].z += a0 * w0.z + a1 * w1.z + a2 * w2.z + a3 * w3.z;
      acc[r].w += a0 * w0.w + a1 * w1.w + a2 * w2.w + a3 * w3.w;
    }
  }

  if (wave > 0) {
#pragma unroll
    for (int r = 0; r < 8; r++)
      redS[(wave - 1) * 512 + r * 64 + lane] = acc[r];
  }
  __syncthreads();
  if (wave == 0) {
#pragma unroll
    for (int r = 0; r < 8; r++) {
      float4 t = acc[r];
#pragma unroll
      for (int w = 0; w < 3; w++) {
        float4 p = redS[w * 512 + r * 64 + lane];
        t.x += p.x; t.y += p.y; t.z += p.z; t.w += p.w;
      }
      size_t gi = (size_t)(r0 + r) * HH + lane;
      float cprev = c1[gi];
      float si = 1.0f / (1.0f + __expf(-t.x));
      float sf = 1.0f / (1.0f + __expf(-t.y));
      float so = 1.0f / (1.0f + __expf(-t.z));
      float cn = sf * cprev + si * tanhf(t.w);
      float hn = so * tanhf(cn);
      c1[gi] = cn;
      Pw[gi * 2 + 1] = hn;
    }
  }
}

// ---------------------------------------------------------------------------
// Fused step kernel: blocks [0, c0blocks) run cell0(t); the rest cell1(t-1).
// LDS: actS (8*4*ASTR floats, cell0 uses half) + redS (3*512 float4).
// ---------------------------------------------------------------------------
__launch_bounds__(256, 4)
__global__ void k_cells(int c0blocks,
                        const int* __restrict__ ell_col,
                        const float* __restrict__ ell_val,
                        const int* __restrict__ ell_cnt,
                        const float2* __restrict__ Pr, float* __restrict__ Pw,
                        float* __restrict__ c0, float* __restrict__ c1,
                        const float* __restrict__ xt, const float* __restrict__ gaxt,
                        const float4* __restrict__ Wg0,
                        const float4* __restrict__ biasg0,
                        const float4* __restrict__ xq0,
                        const float4* __restrict__ Wg1,
                        const float4* __restrict__ biasg1) {
  __shared__ float actS[8 * 4 * ASTR];
  __shared__ float4 redS[3 * 512];
  int b = blockIdx.x;
  if (b < c0blocks) {
    cell0_body(b, actS, redS, ell_col, ell_val, ell_cnt, Pr, Pw, c0,
               xt, gaxt, Wg0, biasg0, xq0);
  } else {
    cell1_body(b - c0blocks, actS, redS, ell_col, ell_val, ell_cnt, Pr, Pw, c1,
               Wg1, biasg1);
  }
}

// ---------------------------------------------------------------------------
// Output projection: out[r,p] = h1[r,:] @ outW[:,p] + outb[p].
// h1 final = P0[..][1] (launch 48 writes P[0].y).
// ---------------------------------------------------------------------------
__launch_bounds__(256)
__global__ void k_out(const float* __restrict__ P0, const float* __restrict__ outW,
                      const float* __restrict__ outb, float* __restrict__ out) {
  int idx = blockIdx.x * 256 + threadIdx.x;
  if (idx >= NN * PP) return;
  int r = idx / PP, p = idx - r * PP;
  float acc = outb[p];
  const float* hrow = P0 + (size_t)r * 128;
#pragma unroll 16
  for (int k = 0; k < HH; k++) acc += hrow[k * 2 + 1] * outW[k * PP + p];
  out[idx] = acc;
}

extern "C" void kernel_launch(void* const* d_in, const int* in_sizes, int n_in,
                              void* d_out, int out_size, void* d_ws, size_t ws_size,
                              hipStream_t stream) {
  const float* x     = (const float*)d_in[0];
  const float* adj   = (const float*)d_in[1];
  const float* gcWi0 = (const float*)d_in[2];
  const float* gcbi0 = (const float*)d_in[3];
  const float* gcWh0 = (const float*)d_in[4];
  const float* gcbh0 = (const float*)d_in[5];
  const float* liWi0 = (const float*)d_in[6];
  const float* libi0 = (const float*)d_in[7];
  const float* liWh0 = (const float*)d_in[8];
  const float* libh0 = (const float*)d_in[9];
  const float* gcWi1 = (const float*)d_in[10];
  const float* gcbi1 = (const float*)d_in[11];
  const float* gcWh1 = (const float*)d_in[12];
  const float* gcbh1 = (const float*)d_in[13];
  const float* liWi1 = (const float*)d_in[14];
  const float* libi1 = (const float*)d_in[15];
  const float* liWh1 = (const float*)d_in[16];
  const float* libh1 = (const float*)d_in[17];
  const float* outW  = (const float*)d_in[18];
  const float* outb  = (const float*)d_in[19];

  char* ws = (char*)d_ws;
  size_t off = 0;
  auto carve = [&](size_t bytes) {
    void* p = ws + off;
    off += (bytes + 255) & ~(size_t)255;
    return p;
  };
  float*  dinv    = (float*)carve((size_t)NN * 4);
  int*    ell_col = (int*)carve((size_t)NN * CAP * 4);
  float*  ell_val = (float*)carve((size_t)NN * CAP * 4);
  int*    ell_cnt = (int*)carve((size_t)NN * 4);
  float*  state   = (float*)carve((size_t)6 * NH * 4);  // P0,P1 (2NH each), c0, c1
  float*  gax     = (float*)carve((size_t)TT * NN * 2 * 4);
  float4* Wg0     = (float4*)carve((size_t)64 * 2 * 64 * 16);
  float4* Wg1     = (float4*)carve((size_t)64 * 4 * 64 * 16);
  float4* biasg0  = (float4*)carve((size_t)64 * 16);
  float4* biasg1  = (float4*)carve((size_t)64 * 16);
  float4* xq0     = (float4*)carve((size_t)256 * 16);

  float* P[2] = {state, state + 2 * NH};
  float* c0 = state + 4 * NH;
  float* c1 = state + 5 * NH;

  k_prep<<<512, 256, 0, stream>>>(gcbi0, gcbh0, libi0, libh0,
                                  gcbi1, gcbh1, libi1, libh1,
                                  gcWh0, liWh0, gcWi1, liWi1, gcWh1, liWh1,
                                  gcWi0, liWi0,
                                  state, Wg0, Wg1, biasg0, biasg1, xq0);
  k_build<<<NN, 256, 0, stream>>>(adj, dinv, ell_col, ell_val, ell_cnt);
  k_scale<<<(NN * CAP) / 256, 256, 0, stream>>>(dinv, ell_col, ell_val);
  k_gax<<<TT * 8, 256, 0, stream>>>(x, ell_col, ell_val, ell_cnt, gax);

  // Software-pipelined step loop: launch k runs {cell0(k) || cell1(k-1)}.
  for (int k = 0; k <= TT; k++) {
    int A = k & 1;
    int c0blocks = (k < TT) ? NN / 8 : 0;
    int c1blocks = (k > 0) ? NN / 8 : 0;
    int grid = c0blocks + c1blocks;
    int tx = (k < TT) ? k : (TT - 1);
    k_cells<<<grid, 256, 0, stream>>>(
        c0blocks, ell_col, ell_val, ell_cnt,
        (const float2*)P[A ^ 1], P[A], c0, c1,
        x + (size_t)tx * NN * 2, gax + (size_t)tx * NN * 2,
        Wg0, biasg0, xq0, Wg1, biasg1);
  }

  // Launch 48 (A=0) wrote h1(47) into P[0].y
  k_out<<<(NN * PP + 255) / 256, 256, 0, stream>>>(P[0], outW, outb, (float*)d_out);
}

// Round 13
// 2156.775 us; speedup vs baseline: 2.8631x; 2.8631x over previous
//
#include <hip/hip_runtime.h>
#include <math.h>

// Problem constants
#define NN 4096
#define TT 48
#define HH 64
#define GG 256   // 4*H
#define PP 12
#define CAP 192  // ELL slots per row, 3 x 64 -> whole-wave chunk loads, no guard
#define NH (NN * HH)

// readlane broadcast: uniform lane index -> SGPR broadcast, off the LDS pipe
__device__ __forceinline__ float bcast_f(float v, int lane) {
  return __int_as_float(__builtin_amdgcn_readlane(__float_as_int(v), lane));
}
__device__ __forceinline__ int bcast_i(int v, int lane) {
  return __builtin_amdgcn_readlane(v, lane);
}

// ---------------------------------------------------------------------------
// h-state: paired buffers P[2], each [N][64][2]: {h0, h1} interleaved.
// Launch k (k=0..48) computes cell0(t=k) [k<48] and cell1(s=k-1) [k>0]:
//   READS only P[(k&1)^1], WRITES only P[k&1] (disjoint float2 slots).
// GATE-QUAD mapping: lane j owns cols {j, j+64, j+128, j+192} = (i,f,o,g) of
// hidden unit j; a row's full gate quad lives in one lane's float4 acc.
// R12 post-mortem: k-split + acc[8] spilled (VGPR capped 64 by launch_bounds,
// 200MB/launch scratch). R13: back to R11 bodies, 4 rows/wave (was 2) —
// halves the per-launch weight L2 stream (768->384MB), improves FMA:RL to
// 4:1, keeps acc at 16 VGPR. NO LDS, NO barriers in cell bodies.
//   Wg0[(k*2+m)*64+j] = float4 gate-quad, m in {gcWh0, liWh0}
//   Wg1[(k*4+m)*64+j] = float4 gate-quad, m in {gcWi1, liWi1, gcWh1, liWh1}
// ---------------------------------------------------------------------------
__launch_bounds__(256)
__global__ void k_prep(const float* gcbi0, const float* gcbh0,
                       const float* libi0, const float* libh0,
                       const float* gcbi1, const float* gcbh1,
                       const float* libi1, const float* libh1,
                       const float* gcWh0, const float* liWh0,
                       const float* gcWi1, const float* liWi1,
                       const float* gcWh1, const float* liWh1,
                       const float* gcWi0, const float* liWi0,
                       float* state, float4* Wg0, float4* Wg1,
                       float4* biasg0, float4* biasg1, float4* xq0) {
  int idx = blockIdx.x * 256 + threadIdx.x;
  int stride = gridDim.x * 256;
  for (int i = idx; i < 6 * NH; i += stride) state[i] = 0.0f;  // P0,P1,c0,c1
  for (int i = idx; i < 64 * 2 * 64; i += stride) {
    int j = i & 63, m = (i >> 6) & 1, k = i >> 7;
    const float* W = m ? liWh0 : gcWh0;
    Wg0[i] = make_float4(W[k * GG + j], W[k * GG + j + 64],
                         W[k * GG + j + 128], W[k * GG + j + 192]);
  }
  for (int i = idx; i < 64 * 4 * 64; i += stride) {
    int j = i & 63, m = (i >> 6) & 3, k = i >> 8;
    const float* W = (m == 0) ? gcWi1 : (m == 1) ? liWi1 : (m == 2) ? gcWh1 : liWh1;
    Wg1[i] = make_float4(W[k * GG + j], W[k * GG + j + 64],
                         W[k * GG + j + 128], W[k * GG + j + 192]);
  }
  if (idx < 64) {
    int j = idx;
    biasg0[j] = make_float4(
        gcbi0[j] + gcbh0[j] + libi0[j] + libh0[j],
        gcbi0[j + 64] + gcbh0[j + 64] + libi0[j + 64] + libh0[j + 64],
        gcbi0[j + 128] + gcbh0[j + 128] + libi0[j + 128] + libh0[j + 128],
        gcbi0[j + 192] + gcbh0[j + 192] + libi0[j + 192] + libh0[j + 192]);
    biasg1[j] = make_float4(
        gcbi1[j] + gcbh1[j] + libi1[j] + libh1[j],
        gcbi1[j + 64] + gcbh1[j + 64] + libi1[j + 64] + libh1[j + 64],
        gcbi1[j + 128] + gcbh1[j + 128] + libi1[j + 128] + libh1[j + 128],
        gcbi1[j + 192] + gcbh1[j + 192] + libi1[j + 192] + libh1[j + 192]);
  } else if (idx < 320) {
    int i = idx - 64;           // i = m*64 + j
    int j = i & 63, m = i >> 6; // m: 0,1 -> gcWi0 row 0/1; 2,3 -> liWi0 row 0/1
    const float* W = (m < 2) ? gcWi0 : liWi0;
    int kk = m & 1;
    xq0[i] = make_float4(W[kk * GG + j], W[kk * GG + j + 64],
                         W[kk * GG + j + 128], W[kk * GG + j + 192]);
  }
}

// ---------------------------------------------------------------------------
// Single adj pass: raw ELL (incl. +I diag) + dinv. Zero-fills ALL CAP slots
// (re-poison semantics: padding must be (col=0, val=0)). cnt padded to x8.
// ---------------------------------------------------------------------------
__launch_bounds__(256)
__global__ void k_build(const float* adj, float* dinv,
                        int* ell_col, float* ell_val, int* ell_cnt) {
  int r = blockIdx.x;
  __shared__ int cnt;
  __shared__ float red[256];
  if (threadIdx.x == 0) cnt = 0;
  __syncthreads();
  const float* row = adj + (size_t)r * NN;
  float s = 0.0f;
  for (int c = threadIdx.x; c < NN; c += 256) {
    float a = row[c];
    if (c == r) a += 1.0f;   // A = adj + I
    s += a;
    if (a != 0.0f) {
      int pos = atomicAdd(&cnt, 1);
      if (pos < CAP) {
        ell_col[(size_t)r * CAP + pos] = c;
        ell_val[(size_t)r * CAP + pos] = a;
      }
    }
  }
  red[threadIdx.x] = s;
  __syncthreads();
  for (int st = 128; st > 0; st >>= 1) {
    if (threadIdx.x < st) red[threadIdx.x] += red[threadIdx.x + st];
    __syncthreads();
  }
  int n = cnt < CAP ? cnt : CAP;
  for (int j = n + (int)threadIdx.x; j < CAP; j += 256) {
    ell_col[(size_t)r * CAP + j] = 0;
    ell_val[(size_t)r * CAP + j] = 0.0f;
  }
  if (threadIdx.x == 0) {
    int npad = (n + 7) & ~7;
    if (npad > CAP) npad = CAP;
    ell_cnt[r] = npad;
    dinv[r] = 1.0f / sqrtf(red[0]);  // rowsum + 1 >= 1
  }
}

__launch_bounds__(256)
__global__ void k_scale(const float* dinv, const int* ell_col, float* ell_val) {
  int idx = blockIdx.x * 256 + threadIdx.x;  // over NN*CAP
  int r = idx / CAP;
  if (r >= NN) return;
  float v = ell_val[idx];
  if (v != 0.0f) ell_val[idx] = v * dinv[r] * dinv[ell_col[idx]];
}

// ---------------------------------------------------------------------------
// Precompute gax[t][r][c] = (A @ x_t)[r][c]. Block = (t, 512-row segment).
// ---------------------------------------------------------------------------
__launch_bounds__(256)
__global__ void k_gax(const float* x, const int* ell_col, const float* ell_val,
                      const int* ell_cnt, float* gax) {
  int t = blockIdx.x >> 3;
  int seg = blockIdx.x & 7;
  __shared__ float xs[NN * 2];
  const float* xt = x + (size_t)t * NN * 2;
  for (int i = threadIdx.x; i < NN * 2; i += 256) xs[i] = xt[i];
  __syncthreads();
  int base = seg * 512 * 2;
  for (int oo = threadIdx.x; oo < 512 * 2; oo += 256) {
    int o = base + oo;
    int r = o >> 1, cmp = o & 1;
    int cnt = ell_cnt[r];
    const int* cp = ell_col + (size_t)r * CAP;
    const float* vp = ell_val + (size_t)r * CAP;
    float acc = 0.0f;
    for (int j = 0; j < cnt; j += 4) {
      acc += vp[j]     * xs[cp[j]     * 2 + cmp];
      acc += vp[j + 1] * xs[cp[j + 1] * 2 + cmp];
      acc += vp[j + 2] * xs[cp[j + 2] * 2 + cmp];
      acc += vp[j + 3] * xs[cp[j + 3] * 2 + cmp];
    }
    gax[(size_t)t * NN * 2 + o] = acc;
  }
}

// ---------------------------------------------------------------------------
// Cell 0 body (wave owns 4 rows end-to-end): barrier-free, LDS-free.
// ---------------------------------------------------------------------------
__device__ __forceinline__ void cell0_body(
    int blk,
    const int* __restrict__ ell_col, const float* __restrict__ ell_val,
    const int* __restrict__ ell_cnt,
    const float2* __restrict__ Pr, float* __restrict__ Pw,
    float* __restrict__ c0,
    const float* __restrict__ xt, const float* __restrict__ gaxt,
    const float4* __restrict__ Wg0, const float4* __restrict__ biasg0,
    const float4* __restrict__ xq0) {
  const int tid = threadIdx.x;
  const int wave = tid >> 6, lane = tid & 63;
  const int r0 = blk * 16 + wave * 4;

  float gacc[4], hl[4];
#pragma unroll
  for (int rr = 0; rr < 4; rr++) {
    int r = r0 + rr;
    int cnt = ell_cnt[r];
    float acc = 0.0f;
#pragma unroll
    for (int chk = 0; chk < 3; chk++) {
      int base = chk * 64;
      if (base < cnt) {
        int lim = cnt - base; if (lim > 64) lim = 64;  // multiple of 8
        int mc = ell_col[(size_t)r * CAP + base + lane];
        float mv = ell_val[(size_t)r * CAP + base + lane];
        for (int m = 0; m < lim; m += 8) {
          float2 ld[8]; float vv[8];
#pragma unroll
          for (int i = 0; i < 8; i++) {
            int cc = bcast_i(mc, m + i);
            vv[i] = bcast_f(mv, m + i);
            ld[i] = Pr[(size_t)cc * 64 + lane];
          }
#pragma unroll
          for (int i = 0; i < 8; i++) acc += vv[i] * ld[i].x;
        }
      }
    }
    gacc[rr] = acc;
    hl[rr] = Pr[(size_t)r * 64 + lane].x;
  }

  float4 acc[4];
  {
    float4 b = biasg0[lane];
    float4 qg0 = xq0[lane], qg1 = xq0[64 + lane];
    float4 ql0 = xq0[128 + lane], ql1 = xq0[192 + lane];
#pragma unroll
    for (int rr = 0; rr < 4; rr++) {
      float xx0 = xt[(size_t)(r0 + rr) * 2];
      float xx1 = xt[(size_t)(r0 + rr) * 2 + 1];
      float gg0 = gaxt[(size_t)(r0 + rr) * 2];
      float gg1 = gaxt[(size_t)(r0 + rr) * 2 + 1];
      acc[rr].x = b.x + gg0 * qg0.x + gg1 * qg1.x + xx0 * ql0.x + xx1 * ql1.x;
      acc[rr].y = b.y + gg0 * qg0.y + gg1 * qg1.y + xx0 * ql0.y + xx1 * ql1.y;
      acc[rr].z = b.z + gg0 * qg0.z + gg1 * qg1.z + xx0 * ql0.z + xx1 * ql1.z;
      acc[rr].w = b.w + gg0 * qg0.w + gg1 * qg1.w + xx0 * ql0.w + xx1 * ql1.w;
    }
  }

  const float4* bw = Wg0 + lane;
#pragma unroll 4
  for (int k = 0; k < 64; k++) {
    float4 w0 = bw[(k * 2 + 0) * 64];
    float4 w1 = bw[(k * 2 + 1) * 64];
#pragma unroll
    for (int rr = 0; rr < 4; rr++) {
      float a0 = bcast_f(gacc[rr], k);
      float a1 = bcast_f(hl[rr], k);
      acc[rr].x += a0 * w0.x + a1 * w1.x;
      acc[rr].y += a0 * w0.y + a1 * w1.y;
      acc[rr].z += a0 * w0.z + a1 * w1.z;
      acc[rr].w += a0 * w0.w + a1 * w1.w;
    }
  }

#pragma unroll
  for (int rr = 0; rr < 4; rr++) {
    size_t gi = (size_t)(r0 + rr) * HH + lane;
    float cprev = c0[gi];
    float si = 1.0f / (1.0f + __expf(-acc[rr].x));
    float sf = 1.0f / (1.0f + __expf(-acc[rr].y));
    float so = 1.0f / (1.0f + __expf(-acc[rr].z));
    float cn = sf * cprev + si * tanhf(acc[rr].w);
    float hn = so * tanhf(cn);
    c0[gi] = cn;
    Pw[gi * 2 + 0] = hn;
  }
}

// ---------------------------------------------------------------------------
// Cell 1 body (wave owns 4 rows): dual gather from paired {h0n,h1old}.
// ---------------------------------------------------------------------------
__device__ __forceinline__ void cell1_body(
    int blk,
    const int* __restrict__ ell_col, const float* __restrict__ ell_val,
    const int* __restrict__ ell_cnt,
    const float2* __restrict__ Pr, float* __restrict__ Pw,
    float* __restrict__ c1,
    const float4* __restrict__ Wg1, const float4* __restrict__ biasg1) {
  const int tid = threadIdx.x;
  const int wave = tid >> 6, lane = tid & 63;
  const int r0 = blk * 16 + wave * 4;

  float ga0[4], ga1[4], hl0[4], hl1[4];
#pragma unroll
  for (int rr = 0; rr < 4; rr++) {
    int r = r0 + rr;
    int cnt = ell_cnt[r];
    float a0 = 0.0f, a1 = 0.0f;
#pragma unroll
    for (int chk = 0; chk < 3; chk++) {
      int base = chk * 64;
      if (base < cnt) {
        int lim = cnt - base; if (lim > 64) lim = 64;  // multiple of 8
        int mc = ell_col[(size_t)r * CAP + base + lane];
        float mv = ell_val[(size_t)r * CAP + base + lane];
        for (int m = 0; m < lim; m += 8) {
          float2 ld[8]; float vv[8];
#pragma unroll
          for (int i = 0; i < 8; i++) {
            int cc = bcast_i(mc, m + i);
            vv[i] = bcast_f(mv, m + i);
            ld[i] = Pr[(size_t)cc * 64 + lane];
          }
#pragma unroll
          for (int i = 0; i < 8; i++) {
            a0 += vv[i] * ld[i].x;
            a1 += vv[i] * ld[i].y;
          }
        }
      }
    }
    ga0[rr] = a0;
    ga1[rr] = a1;
    float2 hh = Pr[(size_t)r * 64 + lane];
    hl0[rr] = hh.x;
    hl1[rr] = hh.y;
  }

  float4 acc[4];
  {
    float4 b = biasg1[lane];
#pragma unroll
    for (int rr = 0; rr < 4; rr++) acc[rr] = b;
  }
  const float4* bw = Wg1 + lane;
#pragma unroll 4
  for (int k = 0; k < 64; k++) {
    float4 w0 = bw[(k * 4 + 0) * 64];
    float4 w1 = bw[(k * 4 + 1) * 64];
    float4 w2 = bw[(k * 4 + 2) * 64];
    float4 w3 = bw[(k * 4 + 3) * 64];
#pragma unroll
    for (int rr = 0; rr < 4; rr++) {
      float a0 = bcast_f(ga0[rr], k);   // (A@h0n)   -> gcWi1
      float a1 = bcast_f(hl0[rr], k);   // h0n       -> liWi1
      float a2 = bcast_f(ga1[rr], k);   // (A@h1old) -> gcWh1
      float a3 = bcast_f(hl1[rr], k);   // h1old     -> liWh1
      acc[rr].x += a0 * w0.x + a1 * w1.x + a2 * w2.x + a3 * w3.x;
      acc[rr].y += a0 * w0.y + a1 * w1.y + a2 * w2.y + a3 * w3.y;
      acc[rr].z += a0 * w0.z + a1 * w1.z + a2 * w2.z + a3 * w3.z;
      acc[rr].w += a0 * w0.w + a1 * w1.w + a2 * w2.w + a3 * w3.w;
    }
  }

#pragma unroll
  for (int rr = 0; rr < 4; rr++) {
    size_t gi = (size_t)(r0 + rr) * HH + lane;
    float cprev = c1[gi];
    float si = 1.0f / (1.0f + __expf(-acc[rr].x));
    float sf = 1.0f / (1.0f + __expf(-acc[rr].y));
    float so = 1.0f / (1.0f + __expf(-acc[rr].z));
    float cn = sf * cprev + si * tanhf(acc[rr].w);
    float hn = so * tanhf(cn);
    c1[gi] = cn;
    Pw[gi * 2 + 1] = hn;
  }
}

// ---------------------------------------------------------------------------
// Fused step kernel: blocks [0, c0blocks) run cell0(t); the rest cell1(t-1).
// Block = 16 rows (4 rows/wave).
// ---------------------------------------------------------------------------
__launch_bounds__(256)
__global__ void k_cells(int c0blocks,
                        const int* __restrict__ ell_col,
                        const float* __restrict__ ell_val,
                        const int* __restrict__ ell_cnt,
                        const float2* __restrict__ Pr, float* __restrict__ Pw,
                        float* __restrict__ c0, float* __restrict__ c1,
                        const float* __restrict__ xt, const float* __restrict__ gaxt,
                        const float4* __restrict__ Wg0,
                        const float4* __restrict__ biasg0,
                        const float4* __restrict__ xq0,
                        const float4* __restrict__ Wg1,
                        const float4* __restrict__ biasg1) {
  int b = blockIdx.x;
  if (b < c0blocks) {
    cell0_body(b, ell_col, ell_val, ell_cnt, Pr, Pw, c0, xt, gaxt,
               Wg0, biasg0, xq0);
  } else {
    cell1_body(b - c0blocks, ell_col, ell_val, ell_cnt, Pr, Pw, c1,
               Wg1, biasg1);
  }
}

// ---------------------------------------------------------------------------
// Output projection: out[r,p] = h1[r,:] @ outW[:,p] + outb[p].
// h1 final = P0[..][1] (launch 48 writes P[0].y).
// ---------------------------------------------------------------------------
__launch_bounds__(256)
__global__ void k_out(const float* __restrict__ P0, const float* __restrict__ outW,
                      const float* __restrict__ outb, float* __restrict__ out) {
  int idx = blockIdx.x * 256 + threadIdx.x;
  if (idx >= NN * PP) return;
  int r = idx / PP, p = idx - r * PP;
  float acc = outb[p];
  const float* hrow = P0 + (size_t)r * 128;
#pragma unroll 16
  for (int k = 0; k < HH; k++) acc += hrow[k * 2 + 1] * outW[k * PP + p];
  out[idx] = acc;
}

extern "C" void kernel_launch(void* const* d_in, const int* in_sizes, int n_in,
                              void* d_out, int out_size, void* d_ws, size_t ws_size,
                              hipStream_t stream) {
  const float* x     = (const float*)d_in[0];
  const float* adj   = (const float*)d_in[1];
  const float* gcWi0 = (const float*)d_in[2];
  const float* gcbi0 = (const float*)d_in[3];
  const float* gcWh0 = (const float*)d_in[4];
  const float* gcbh0 = (const float*)d_in[5];
  const float* liWi0 = (const float*)d_in[6];
  const float* libi0 = (const float*)d_in[7];
  const float* liWh0 = (const float*)d_in[8];
  const float* libh0 = (const float*)d_in[9];
  const float* gcWi1 = (const float*)d_in[10];
  const float* gcbi1 = (const float*)d_in[11];
  const float* gcWh1 = (const float*)d_in[12];
  const float* gcbh1 = (const float*)d_in[13];
  const float* liWi1 = (const float*)d_in[14];
  const float* libi1 = (const float*)d_in[15];
  const float* liWh1 = (const float*)d_in[16];
  const float* libh1 = (const float*)d_in[17];
  const float* outW  = (const float*)d_in[18];
  const float* outb  = (const float*)d_in[19];

  char* ws = (char*)d_ws;
  size_t off = 0;
  auto carve = [&](size_t bytes) {
    void* p = ws + off;
    off += (bytes + 255) & ~(size_t)255;
    return p;
  };
  float*  dinv    = (float*)carve((size_t)NN * 4);
  int*    ell_col = (int*)carve((size_t)NN * CAP * 4);
  float*  ell_val = (float*)carve((size_t)NN * CAP * 4);
  int*    ell_cnt = (int*)carve((size_t)NN * 4);
  float*  state   = (float*)carve((size_t)6 * NH * 4);  // P0,P1 (2NH each), c0, c1
  float*  gax     = (float*)carve((size_t)TT * NN * 2 * 4);
  float4* Wg0     = (float4*)carve((size_t)64 * 2 * 64 * 16);
  float4* Wg1     = (float4*)carve((size_t)64 * 4 * 64 * 16);
  float4* biasg0  = (float4*)carve((size_t)64 * 16);
  float4* biasg1  = (float4*)carve((size_t)64 * 16);
  float4* xq0     = (float4*)carve((size_t)256 * 16);

  float* P[2] = {state, state + 2 * NH};
  float* c0 = state + 4 * NH;
  float* c1 = state + 5 * NH;

  k_prep<<<512, 256, 0, stream>>>(gcbi0, gcbh0, libi0, libh0,
                                  gcbi1, gcbh1, libi1, libh1,
                                  gcWh0, liWh0, gcWi1, liWi1, gcWh1, liWh1,
                                  gcWi0, liWi0,
                                  state, Wg0, Wg1, biasg0, biasg1, xq0);
  k_build<<<NN, 256, 0, stream>>>(adj, dinv, ell_col, ell_val, ell_cnt);
  k_scale<<<(NN * CAP) / 256, 256, 0, stream>>>(dinv, ell_col, ell_val);
  k_gax<<<TT * 8, 256, 0, stream>>>(x, ell_col, ell_val, ell_cnt, gax);

  // Software-pipelined step loop: launch k runs {cell0(k) || cell1(k-1)}.
  for (int k = 0; k <= TT; k++) {
    int A = k & 1;
    int c0blocks = (k < TT) ? NN / 16 : 0;
    int c1blocks = (k > 0) ? NN / 16 : 0;
    int grid = c0blocks + c1blocks;
    int tx = (k < TT) ? k : (TT - 1);
    k_cells<<<grid, 256, 0, stream>>>(
        c0blocks, ell_col, ell_val, ell_cnt,
        (const float2*)P[A ^ 1], P[A], c0, c1,
        x + (size_t)tx * NN * 2, gax + (size_t)tx * NN * 2,
        Wg0, biasg0, xq0, Wg1, biasg1);
  }

  // Launch 48 (A=0) wrote h1(47) into P[0].y
  k_out<<<(NN * PP + 255) / 256, 256, 0, stream>>>(P[0], outW, outb, (float*)d_out);
}